// Round 7
// baseline (531.236 us; speedup 1.0000x reference)
//
#include <hip/hip_runtime.h>
#include <hip/hip_bf16.h>

// ---------------------------------------------------------------------------
// DenseCorr2d_full — FUSED corr+merge, register-lean 256-thr (round 10).
//
// Residency model from r0..r9 counters: waves/SIMD ~= 256 / reported VGPR
// (96->2, 60->4, 32->8; LDS never bound). So this round minimizes registers
// and uses 256-thr blocks for fine-grained packing:
//   * tile 64co x 4y x 16x, grid 2048, slab = 2cm x 8, LDS 14.6KB
//   * tp pre-converted to bf16 (tp_kernel) -> corr A-frags are 16B loads
//   * bq in quarters (8 regs live, asm-opaqued vs LICM), single acc chain
//   * merge: inline af loads (no prefetch regs), acc[4] = 16 regs
//   * __launch_bounds__(256,5): 51-VGPR budget vs ~48 hand-counted live
// ws layout: Wb bf16 [9][64][256] (294912B) then tpb bf16 [8][16][256].
// ---------------------------------------------------------------------------

typedef __attribute__((ext_vector_type(4))) float  f32x4;
typedef __attribute__((ext_vector_type(8))) short  bf16x8;

__device__ inline unsigned int pack_bf16x2(float a, float b) {
    unsigned int ua = __builtin_bit_cast(unsigned int, a);
    unsigned int ub = __builtin_bit_cast(unsigned int, b);
    ua = (ua + 0x7fffu + ((ua >> 16) & 1u)) >> 16;   // RNE
    ub = (ub + 0x7fffu + ((ub >> 16) & 1u)) >> 16;
    return ua | (ub << 16);
}
__device__ inline unsigned short cvt1(float f) {
    unsigned int u = __builtin_bit_cast(unsigned int, f);
    return (unsigned short)((u + 0x7fffu + ((u >> 16) & 1u)) >> 16);
}

// ---------------- W transform: [co][cin][3][3] fp32 -> Wb[kk][co][256] bf16 -
__global__ __launch_bounds__(256) void wt_kernel(
    const float* __restrict__ W, unsigned short* __restrict__ Wb)
{
    int idx = (int)blockIdx.x * 256 + (int)threadIdx.x;   // < 9*64*256
    int c  = idx & 255;
    int rem = idx >> 8;
    int co = rem % 64;
    int kk = rem / 64;
    Wb[idx] = cvt1(W[(size_t)co * 2304 + (size_t)c * 9 + kk]);
}

// ---------------- tp transform: [8][16][16][16] fp32 -> bf16 (same layout) --
__global__ __launch_bounds__(256) void tp_kernel(
    const float* __restrict__ tp, unsigned short* __restrict__ tpb)
{
    int idx = (int)blockIdx.x * 256 + (int)threadIdx.x;   // < 32768
    tpb[idx] = cvt1(tp[idx]);
}

// ---------------- Fused corr + 3x3 SAME merge conv --------------------------
__global__ __launch_bounds__(256, 5) void fused_mfma(
    const unsigned short* __restrict__ tpb, const float* __restrict__ tm,
    const unsigned short* __restrict__ Wb, const float* __restrict__ bias,
    float* __restrict__ out)
{
    // tm halo, 2 parity copies: [cm 2][par 2][row 22][pitch 34] = 5984 B
    __shared__ __align__(16) unsigned short smT[2 * 2 * 22 * 34];
    // corr slab: [pix 108 = 6r x 18c][40 ch-pitch] = 8640 B
    __shared__ __align__(16) unsigned short smC[108 * 40];

    const int t    = threadIdx.x;
    const int wave = t >> 6, lane = t & 63;
    const int n    = lane & 15, quad = lane >> 4;
    const int qh   = quad >> 1, jq = quad & 1;

    const int x0 = (int)blockIdx.x << 4;   // 0..112
    const int y0 = (int)blockIdx.y << 2;   // 0..124
    const int b  = (int)blockIdx.z;

    f32x4 acc[4];                          // merge accumulators [ct]
#pragma unroll
    for (int a = 0; a < 4; ++a) acc[a] = (f32x4){0.f, 0.f, 0.f, 0.f};

    const unsigned short* tpk = tpb + (((size_t)(b * 16 + n)) << 8);

#pragma unroll 1
    for (int s = 0; s < 8; ++s) {
        // ---- 1. stage tm halo, cm = 2s..2s+1: rows y0-1..y0+20,
        //         cols x0-1..x0+32 (edge-clamped), parity-shifted copy ----
        {
            const float* tmb = tm + ((size_t)(b * 16 + (s << 1)) << 14);
#pragma unroll 1
            for (int k = 0; k < 6; ++k) {            // 6*256 = 1536 >= 1496
                int e  = t + (k << 8);
                int ec = e < 1496 ? e : 1495;        // dup-clamp (same value)
                int cm = ec >= 748 ? 1 : 0;
                int rem = ec - (cm ? 748 : 0);
                int r   = rem / 34;
                int c   = rem - 34 * r;
                int gy = y0 - 1 + r; gy = gy < 0 ? 0 : (gy > 127 ? 127 : gy);
                int gx = x0 - 1 + c; gx = gx < 0 ? 0 : (gx > 127 ? 127 : gx);
                unsigned short h = cvt1(tmb[((size_t)cm << 14) + (gy << 7) + gx]);
                int a0 = cm * 1496 + r * 34 + c;     // parity-0 plane
                smT[a0] = h;                         // copy1[c-1] = tm[c]
                if (c > 0) smT[a0 + 747] = h;        // +748 plane, -1 col
            }
        }
        __syncthreads();   // smT ready; all waves past merge(s-1) -> smC free

        // ---- 2. corr: 14 groups = 2cm x 7 pixel-tiles over 4 waves x 4 ----
        {
            const unsigned* smTd = (const unsigned*)smT;
#pragma unroll 1
            for (int i = 0; i < 4; ++i) {
                const int g = (i << 2) + wave;        // 0..15
                if (g < 14) {
                    const int j  = g & 1;             // cm_local 0/1
                    const int tl = g >> 1;            // pixel tile 0..6
                    const int p  = (tl << 4) + n;     // halo pixel 0..111
                    const int pc = p < 108 ? p : 107; // clamp tail (no store)
                    const int py = pc / 18;           // 0..5
                    const int px = pc - 18 * py;      // 0..17
                    const int pl = px & 1;            // parity plane
                    // dword base: [j][pl][row=py+qh][((px-pl)/2) + jq*4]
                    const int base = (j * 2 + pl) * 374 + (py + qh) * 17
                                   + ((px - pl) >> 1) + (jq << 2);
                    f32x4 a4 = (f32x4){0.f, 0.f, 0.f, 0.f};
#pragma unroll 1
                    for (int kq = 0; kq < 4; ++kq) {  // bq quarters: kc=2kq,2kq+1
                        const unsigned short* kp =
                            tpk + (kq << 6) + (qh << 4) + (jq << 3);
                        asm volatile("" : "+v"(kp));  // keep 8-reg live window
                        bf16x8 q0 = *(const bf16x8*)kp;
                        bf16x8 q1 = *(const bf16x8*)(kp + 32);
                        const int d0 = base + kq * 68;    // +2 rows per kc
                        union { uint4 u; bf16x8 h; } f0, f1;
                        f0.u.x = smTd[d0];      f0.u.y = smTd[d0 + 1];
                        f0.u.z = smTd[d0 + 2];  f0.u.w = smTd[d0 + 3];
                        f1.u.x = smTd[d0 + 34]; f1.u.y = smTd[d0 + 35];
                        f1.u.z = smTd[d0 + 36]; f1.u.w = smTd[d0 + 37];
                        a4 = __builtin_amdgcn_mfma_f32_16x16x32_bf16(
                            q0, f0.h, a4, 0, 0, 0);
                        a4 = __builtin_amdgcn_mfma_f32_16x16x32_bf16(
                            q1, f1.h, a4, 0, 0, 0);
                    }
                    // D[row=quad*4+r = ct][col=n = pixel]; slot = j*16+quad*4+r
                    const int gy = y0 - 1 + py, gx = x0 - 1 + px;
                    const bool valid = ((unsigned)gy < 128u) && ((unsigned)gx < 128u);
                    uint2 v;
                    v.x = valid ? pack_bf16x2(a4[0], a4[1]) : 0u;  // SAME pad
                    v.y = valid ? pack_bf16x2(a4[2], a4[3]) : 0u;
                    if (p < 108)
                        *(uint2*)&smC[p * 40 + (j << 4) + (quad << 2)] = v;
                }
            }
        }
        __syncthreads();   // smC ready; smT free for next slab's staging

        // ---- 3. merge on slab channels c = 32s + quad*8 + e ----
        {
#pragma unroll 1
            for (int kk = 0; kk < 9; ++kk) {
                const int dy = (kk * 11) >> 5;        // kk/3
                const int dx = kk - 3 * dy;
                const unsigned short* wk = Wb + (size_t)kk * 16384
                                         + (size_t)n * 256 + (s << 5) + (quad << 3);
                bf16x8 af0 = *(const bf16x8*)(wk);
                bf16x8 af1 = *(const bf16x8*)(wk + 4096);
                bf16x8 af2 = *(const bf16x8*)(wk + 8192);
                bf16x8 af3 = *(const bf16x8*)(wk + 12288);
                const int prow = wave + dy;           // wave = out row, 0..5
                const int pcol = n + dx;              // 0..17
                bf16x8 bf = *(const bf16x8*)&smC[(prow * 18 + pcol) * 40
                                                 + (quad << 3)];
                acc[0] = __builtin_amdgcn_mfma_f32_16x16x32_bf16(af0, bf, acc[0], 0, 0, 0);
                acc[1] = __builtin_amdgcn_mfma_f32_16x16x32_bf16(af1, bf, acc[1], 0, 0, 0);
                acc[2] = __builtin_amdgcn_mfma_f32_16x16x32_bf16(af2, bf, acc[2], 0, 0, 0);
                acc[3] = __builtin_amdgcn_mfma_f32_16x16x32_bf16(af3, bf, acc[3], 0, 0, 0);
            }
        }
        // next slab: smT write happens after this iteration's barriers, so
        // corr(s) readers are done; smC write only after next bar1.
    }

    // ---- epilogue: D[row=quad*4+r = co][col=n], + bias, fp32 out ----
#pragma unroll
    for (int ct = 0; ct < 4; ++ct) {
        const int y   = y0 + wave;
        const int x   = x0 + n;
        const int co0 = (ct << 4) + (quad << 2);
        float* op = out + (((size_t)((b << 6) + co0) << 7) + y) * 128 + x;
#pragma unroll
        for (int r = 0; r < 4; ++r)
            op[(size_t)r << 14] = acc[ct][r] + bias[co0 + r];
    }
}

extern "C" void kernel_launch(void* const* d_in, const int* in_sizes, int n_in,
                              void* d_out, int out_size, void* d_ws, size_t ws_size,
                              hipStream_t stream)
{
    const float* tp   = (const float*)d_in[0];   // template [8,16,16,16]
    const float* tm   = (const float*)d_in[1];   // tomatch  [8,16,128,128]
    const float* Wt   = (const float*)d_in[2];   // W        [64,256,3,3]
    const float* bias = (const float*)d_in[3];   // b        [64]
    float* out = (float*)d_out;                  // [8,64,128,128] fp32

    unsigned short* Wb  = (unsigned short*)d_ws;          // 294912 B
    unsigned short* tpb = Wb + (size_t)9 * 64 * 256;      // 65536 B

    wt_kernel<<<dim3(576), dim3(256), 0, stream>>>(Wt, Wb);
    tp_kernel<<<dim3(128), dim3(256), 0, stream>>>(tp, tpb);
    fused_mfma<<<dim3(8, 32, 8), dim3(256), 0, stream>>>(tpb, tm, Wb, bias, out);
}

// Round 9
// 200.047 us; speedup vs baseline: 2.6556x; 2.6556x over previous
//
#include <hip/hip_runtime.h>
#include <hip/hip_bf16.h>

// ---------------------------------------------------------------------------
// DenseCorr2d_full — FUSED corr+merge, operand-traffic-minimized (round 12 =
// round 11 with two staging bugfixes: uint4 seg stride 8 shorts not 16
// (was OOB LDS write clobbering smT/smC -> NaN), and a __syncthreads()
// after smP staging before first use).
//
// Diagnosis from r5..r10 counters: dur scales with per-CU operand re-read
// traffic (L1 line-spread reads + LDS insts), NOT with occupancy (93% occ
// was slowest). This round minimizes reads per MFMA:
//  * corr B-frag = ONE ds_read2_b64 (4 shift-copies; plane 1360 sh = 2720B
//    ≡ 32 mod 128B: 16 n-lanes land on 16 distinct 8B slots, conflict-free)
//    [was 4x ds_read_b32 per MFMA = 54us of LDS pipe]
//  * merge = r0-verbatim acc[4][4] 4-wave scheme: 8 frag-reads / 16 MFMA
//  * tp staged once to LDS (pitch 264: 16B-aligned, 2-way banks = free);
//    corr A-frags single b128, reloaded per slab (asm-opaqued vs LICM)
//  * 256-thr blocks, ~8 waves/CU: LOW occupancy by design (less L1 thrash)
// ws layout: Wb bf16 [9][64][256] (294912B) then tpb bf16 [8][16][256].
// ---------------------------------------------------------------------------

typedef __attribute__((ext_vector_type(4))) float  f32x4;
typedef __attribute__((ext_vector_type(8))) short  bf16x8;

__device__ inline unsigned int pack_bf16x2(float a, float b) {
    unsigned int ua = __builtin_bit_cast(unsigned int, a);
    unsigned int ub = __builtin_bit_cast(unsigned int, b);
    ua = (ua + 0x7fffu + ((ua >> 16) & 1u)) >> 16;   // RNE
    ub = (ub + 0x7fffu + ((ub >> 16) & 1u)) >> 16;
    return ua | (ub << 16);
}
__device__ inline unsigned short cvt1(float f) {
    unsigned int u = __builtin_bit_cast(unsigned int, f);
    return (unsigned short)((u + 0x7fffu + ((u >> 16) & 1u)) >> 16);
}

// ---------------- W transform: [co][cin][3][3] fp32 -> Wb[kk][co][256] bf16 -
__global__ __launch_bounds__(256) void wt_kernel(
    const float* __restrict__ W, unsigned short* __restrict__ Wb)
{
    int idx = (int)blockIdx.x * 256 + (int)threadIdx.x;   // < 9*64*256
    int c  = idx & 255;
    int rem = idx >> 8;
    int co = rem % 64;
    int kk = rem / 64;
    Wb[idx] = cvt1(W[(size_t)co * 2304 + (size_t)c * 9 + kk]);
}

// ---------------- tp transform: [8][16][16][16] fp32 -> bf16 (same layout) --
__global__ __launch_bounds__(256) void tp_kernel(
    const float* __restrict__ tp, unsigned short* __restrict__ tpb)
{
    int idx = (int)blockIdx.x * 256 + (int)threadIdx.x;   // < 32768
    tpb[idx] = cvt1(tp[idx]);
}

// ---------------- Fused corr + 3x3 SAME merge conv --------------------------
__global__ __launch_bounds__(256) void fused_mfma(
    const unsigned short* __restrict__ tpb, const float* __restrict__ tm,
    const unsigned short* __restrict__ Wb, const float* __restrict__ bias,
    float* __restrict__ out)
{
    // tm halo, 4 shift-copies: [cm 2][copy 4][plane 1360 sh] = 21760 B
    // (row pitch 52, 25 rows; plane stride 2720B ≡ 32 mod 128)
    __shared__ __align__(16) unsigned short smT[2 * 4 * 1360];
    // corr slab: [pix 340 = 10r x 34c][40 ch-pitch] = 27200 B
    __shared__ __align__(16) unsigned short smC[340 * 40];
    // tp for this b: [ct 16][pitch 264] = 8448 B
    __shared__ __align__(16) unsigned short smP[16 * 264];

    const int t    = threadIdx.x;
    const int wave = t >> 6, lane = t & 63;
    const int n    = lane & 15, quad = lane >> 4;
    const int qh   = quad >> 1, jq = quad & 1;

    const int x0 = (int)blockIdx.x << 5;   // 0..96
    const int y0 = (int)blockIdx.y << 3;   // 0..120
    const int b  = (int)blockIdx.z;

    // ---- stage tp (bf16) into smP: 512 x 16B (=8-short) segments ----
    {
        const unsigned short* src = tpb + ((size_t)b << 12);
#pragma unroll
        for (int k = 0; k < 2; ++k) {
            int sid = t + (k << 8);            // 0..511
            int row = sid >> 5, seg = sid & 31;
            *(uint4*)&smP[row * 264 + (seg << 3)] =          // 8-short stride
                *(const uint4*)(src + row * 256 + (seg << 3));
        }
    }
    __syncthreads();                           // smP visible to all waves

    f32x4 acc[4][4];                       // merge accumulators [ct][nt]
#pragma unroll
    for (int a = 0; a < 4; ++a)
#pragma unroll
        for (int q = 0; q < 4; ++q) acc[a][q] = (f32x4){0.f, 0.f, 0.f, 0.f};

#pragma unroll 1
    for (int s = 0; s < 8; ++s) {
        // ---- 1. stage tm halo cm = 2s,2s+1: rows y0-1..y0+23 (25),
        //         cols x0-1..x0+47 (49), edge-clamped, 4 shift-copies ----
        {
            const float* tmb = tm + ((size_t)(b * 16 + (s << 1)) << 14);
#pragma unroll 1
            for (int e = t; e < 2450; e += 256) {     // 2cm * 25r * 49c
                int cm  = e >= 1225 ? 1 : 0;
                int rem = e - (cm ? 1225 : 0);
                int r   = rem / 49;
                int c   = rem - 49 * r;
                int gy = y0 - 1 + r; gy = gy < 0 ? 0 : (gy > 127 ? 127 : gy);
                int gx = x0 - 1 + c; gx = gx < 0 ? 0 : (gx > 127 ? 127 : gx);
                unsigned short h = cvt1(tmb[((size_t)cm << 14) + (gy << 7) + gx]);
                int a0 = cm * 5440 + r * 52 + c;      // copy-0 plane
                smT[a0] = h;                          // copy cs at +1360cs - cs
                if (c >= 1) smT[a0 + 1359] = h;
                if (c >= 2) smT[a0 + 2718] = h;
                if (c >= 3) smT[a0 + 4077] = h;
            }
        }

        // ---- corr A-frags from smP (single b128 each; opaqued so the 32
        //      regs don't stay live across merge) ----
        bf16x8 bq[8];
        {
            const unsigned short* pp = &smP[n * 264 + (qh << 4) + (jq << 3)];
            asm volatile("" : "+v"(pp));              // defeat cross-slab LICM
#pragma unroll
            for (int kc = 0; kc < 8; ++kc)
                bq[kc] = *(const bf16x8*)(pp + (kc << 5));
        }
        __syncthreads();   // smT ready; all waves past merge(s-1) -> smC free

        // ---- 2. corr: 44 groups = 2cm x 22 pixel-tiles over 4 waves ----
#pragma unroll 1
        for (int i = 0; i < 11; ++i) {
            const int g  = wave * 11 + i;         // 0..43
            const int j  = g / 22;                // cm_local 0/1
            const int tl = g - 22 * j;            // pixel tile 0..21
            const int p  = (tl << 4) + n;         // flat halo pixel 0..351
            const int pc = p < 340 ? p : 339;     // clamp tail (no store)
            const int py = pc / 34;               // 0..9
            const int px = pc - 34 * py;          // 0..33
            const int cs = px & 3;                // shift-copy select
            // copy cs holds col v at v-cs; window (px&~3)+jq*8 is 8B-aligned
            const int base = j * 5440 + cs * 1360 + (py + qh) * 52
                           + (px & ~3) + (jq << 3);
            f32x4 a4a = (f32x4){0.f, 0.f, 0.f, 0.f};
            f32x4 a4b = (f32x4){0.f, 0.f, 0.f, 0.f};
#pragma unroll
            for (int kc = 0; kc < 8; ++kc) {
                const uint2* qp = (const uint2*)&smT[base + kc * 104];
                uint2 lo = qp[0];                 // ds_read2_b64 pair
                uint2 hi = qp[1];
                union { uint4 u; bf16x8 h; } fr;
                fr.u.x = lo.x; fr.u.y = lo.y; fr.u.z = hi.x; fr.u.w = hi.y;
                if (kc & 1)
                    a4b = __builtin_amdgcn_mfma_f32_16x16x32_bf16(
                        bq[kc], fr.h, a4b, 0, 0, 0);
                else
                    a4a = __builtin_amdgcn_mfma_f32_16x16x32_bf16(
                        bq[kc], fr.h, a4a, 0, 0, 0);
            }
            f32x4 a4 = a4a + a4b;
            // D[row=quad*4+r = ct][col=n = pixel]; ch-slot = j*16+quad*4+r
            const int gy = y0 - 1 + py, gx = x0 - 1 + px;
            const bool valid = ((unsigned)gy < 128u) && ((unsigned)gx < 128u);
            uint2 v;
            v.x = valid ? pack_bf16x2(a4[0], a4[1]) : 0u;  // SAME-pad zeros
            v.y = valid ? pack_bf16x2(a4[2], a4[3]) : 0u;
            if (p < 340)
                *(uint2*)&smC[p * 40 + (j << 4) + (quad << 2)] = v;
        }
        __syncthreads();   // smC ready; smT free for next slab's staging

        // ---- 3. merge on slab channels c0 = 32s (r0-verbatim acc[4][4]) ----
        {
            const unsigned short* wpb = Wb + (size_t)n * 256 + (s << 5) + (quad << 3);
#pragma unroll 1
            for (int kk = 0; kk < 9; ++kk) {
                const int dy = (kk * 11) >> 5;        // kk/3
                const int dx = kk - 3 * dy;
                bf16x8 af[4];
#pragma unroll
                for (int ct = 0; ct < 4; ++ct)
                    af[ct] = *(const bf16x8*)(wpb + (size_t)kk * 16384
                                                  + (size_t)ct * 4096);
#pragma unroll
                for (int nt = 0; nt < 4; ++nt) {
                    const int prow = 2 * wave + (nt >> 1) + dy;   // 0..9
                    const int pcol = ((nt & 1) << 4) + n + dx;    // 0..33
                    bf16x8 bf = *(const bf16x8*)&smC[(prow * 34 + pcol) * 40
                                                     + (quad << 3)];
#pragma unroll
                    for (int ct = 0; ct < 4; ++ct)
                        acc[ct][nt] = __builtin_amdgcn_mfma_f32_16x16x32_bf16(
                            af[ct], bf, acc[ct][nt], 0, 0, 0);
                }
            }
        }
        // next slab: smT staging starts only after all waves passed bar2 (so
        // corr(s) readers done); smC rewritten only after next bar1.
    }

    // ---- epilogue: D[row=quad*4+r = co][col=n], + bias, fp32 out ----
#pragma unroll
    for (int ct = 0; ct < 4; ++ct) {
#pragma unroll
        for (int nt = 0; nt < 4; ++nt) {
            const int y   = y0 + 2 * wave + (nt >> 1);
            const int x   = x0 + ((nt & 1) << 4) + n;
            const int co0 = (ct << 4) + (quad << 2);
            float* op = out + (((size_t)((b << 6) + co0) << 7) + y) * 128 + x;
#pragma unroll
            for (int r = 0; r < 4; ++r)
                op[(size_t)r << 14] = acc[ct][nt][r] + bias[co0 + r];
        }
    }
}

extern "C" void kernel_launch(void* const* d_in, const int* in_sizes, int n_in,
                              void* d_out, int out_size, void* d_ws, size_t ws_size,
                              hipStream_t stream)
{
    const float* tp   = (const float*)d_in[0];   // template [8,16,16,16]
    const float* tm   = (const float*)d_in[1];   // tomatch  [8,16,128,128]
    const float* Wt   = (const float*)d_in[2];   // W        [64,256,3,3]
    const float* bias = (const float*)d_in[3];   // b        [64]
    float* out = (float*)d_out;                  // [8,64,128,128] fp32

    unsigned short* Wb  = (unsigned short*)d_ws;          // 294912 B
    unsigned short* tpb = Wb + (size_t)9 * 64 * 256;      // 65536 B

    wt_kernel<<<dim3(576), dim3(256), 0, stream>>>(Wt, Wb);
    tp_kernel<<<dim3(128), dim3(256), 0, stream>>>(tp, tpb);
    fused_mfma<<<dim3(4, 16, 8), dim3(256), 0, stream>>>(tpb, tm, Wb, bias, out);
}